// Round 14
// baseline (122.060 us; speedup 1.0000x reference)
//
#include <hip/hip_runtime.h>
#include <cstdint>
#include <cstddef>

// B=32, S=2048, P=256, N=256, K=8, L=4, M_out=1024
// Factorized: v_k = bf16(W^{8-k}) @ X   (stage 1, reads transposed Xt)
//             dec[l] = Pb[l] @ (sum_k we[l,k] v_k)   (stage 2, combine fused
//                      in-LDS just-in-time -- c never materialized in HBM)
// out = dec + mean*(1-rowsumA) + b_enc*std  (affine fold; rowsums of ROUNDED maps)
// R14 = R13 + combine kernel deleted: gemm2c builds c-tiles in LDS per K-step
// (reg-load 8 vt slices early, weighted sum, ds_write macro-row layout).
// Finalize (mean/std/rsA) back in gemm_v tail (r8-proven).

typedef unsigned short ushort_t;
typedef unsigned int uint_t;
typedef __attribute__((ext_vector_type(8))) short bf16x8;
typedef __attribute__((ext_vector_type(16))) float f32x16;

__device__ __forceinline__ ushort_t f32_to_bf16(float f) {
    uint_t u = __float_as_uint(f);
    u += 0x7FFFu + ((u >> 16) & 1u);   // RNE
    return (ushort_t)(u >> 16);
}
__device__ __forceinline__ float bf16_to_f32(ushort_t h) {
    return __uint_as_float((uint_t)h << 16);
}

// ---------------- powers + bf16 convert + rowsums, fused ----------------
struct PowOps { int sa[4]; int sb[4]; int sd[4]; int ed[4]; };

__global__ void powmulc(const float* __restrict__ Wb, float* __restrict__ Pw,
                        ushort_t* __restrict__ Pb, float* __restrict__ prs, PowOps ops) {
    __shared__ float As[4 * 256];
    __shared__ float red[4][4];
    const int mat = blockIdx.x;
    const int r0  = blockIdx.y * 4;
    const int tid = threadIdx.x;
    const int e   = ops.ed[mat];
    const int sa  = ops.sa[mat];
    float a[4];
    if (sa == -2) {
#pragma unroll
        for (int i = 0; i < 4; ++i) a[i] = (r0 + i == tid) ? 1.0f : 0.0f;
    } else if (sa == -3) {
#pragma unroll
        for (int i = 0; i < 4; ++i) a[i] = Wb[(size_t)(r0 + i) * 256 + tid];
    } else {
        const float* A  = (sa < 0) ? Wb : Pw + (size_t)sa * 65536;
        const float* Bm = (ops.sb[mat] < 0) ? Wb : Pw + (size_t)ops.sb[mat] * 65536;
#pragma unroll
        for (int i = 0; i < 4; ++i) As[i * 256 + tid] = A[(size_t)(r0 + i) * 256 + tid];
        __syncthreads();
        float a0 = 0.f, a1 = 0.f, a2 = 0.f, a3 = 0.f;
        for (int p = 0; p < 256; p += 8) {
            float bv[8];
#pragma unroll
            for (int u = 0; u < 8; ++u) bv[u] = Bm[(size_t)(p + u) * 256 + tid];
#pragma unroll
            for (int u = 0; u < 8; ++u) {
                a0 += As[0 * 256 + p + u] * bv[u];
                a1 += As[1 * 256 + p + u] * bv[u];
                a2 += As[2 * 256 + p + u] * bv[u];
                a3 += As[3 * 256 + p + u] * bv[u];
            }
        }
        a[0] = a0; a[1] = a1; a[2] = a2; a[3] = a3;
        if (ops.sd[mat] >= 0) {
            float* C = Pw + (size_t)ops.sd[mat] * 65536;
#pragma unroll
            for (int i = 0; i < 4; ++i) C[(size_t)(r0 + i) * 256 + tid] = a[i];
        }
        __syncthreads();
    }
    const int lane = tid & 63, wv = tid >> 6;
    float rs[4];
#pragma unroll
    for (int i = 0; i < 4; ++i) {
        const ushort_t h = f32_to_bf16(a[i]);
        Pb[(size_t)e * 65536 + (size_t)(r0 + i) * 256 + tid] = h;
        float v = bf16_to_f32(h);
        v += __shfl_xor(v, 1);  v += __shfl_xor(v, 2);  v += __shfl_xor(v, 4);
        v += __shfl_xor(v, 8);  v += __shfl_xor(v, 16); v += __shfl_xor(v, 32);
        rs[i] = v;
    }
    if (lane == 0) {
#pragma unroll
        for (int i = 0; i < 4; ++i) red[i][wv] = rs[i];
    }
    __syncthreads();
    if (tid < 4) prs[e * 256 + r0 + tid] = red[tid][0] + red[tid][1] + red[tid][2] + red[tid][3];
}

// ---------------- prep: transpose RAW x + bf16 convert + stats partials ----------------
__global__ void prep(const float* __restrict__ x, ushort_t* __restrict__ Xt,
                     float* __restrict__ ps1, float* __restrict__ ps2) {
    __shared__ float lds[64 * 65];
    __shared__ float red1[16 * 64];
    __shared__ float red2[16 * 64];
    const int bid = blockIdx.x;
    const int st = bid & 31;
    const int nt = (bid >> 5) & 3;
    const int b  = bid >> 7;
    const int tid = threadIdx.x;
    const int c = tid & 15, r = tid >> 4;
    const int s0 = st * 64;
    float s1[4] = {0,0,0,0}, s2[4] = {0,0,0,0};
#pragma unroll
    for (int it = 0; it < 4; ++it) {
        const int ii = r + it * 16;
        const float4 v = *(const float4*)(x + ((size_t)b * 2048 + s0 + ii) * 256 + nt * 64 + c * 4);
        const float vv[4] = {v.x, v.y, v.z, v.w};
#pragma unroll
        for (int jj = 0; jj < 4; ++jj) {
            lds[ii * 65 + c * 4 + jj] = vv[jj];
            s1[jj] += vv[jj]; s2[jj] += vv[jj] * vv[jj];
        }
    }
#pragma unroll
    for (int jj = 0; jj < 4; ++jj) { red1[r * 64 + c * 4 + jj] = s1[jj]; red2[r * 64 + c * 4 + jj] = s2[jj]; }
    __syncthreads();
    if (tid < 64) {
        float a = 0.f, q = 0.f;
#pragma unroll
        for (int rr = 0; rr < 16; ++rr) { a += red1[rr * 64 + tid]; q += red2[rr * 64 + tid]; }
        const size_t o = (size_t)st * 8192 + b * 256 + nt * 64 + tid;
        ps1[o] = a; ps2[o] = q;
    }
#pragma unroll
    for (int step = 0; step < 8; ++step) {
        const int npr = step * 8 + (tid >> 5);
        const int sp  = (tid & 31) * 2;
        const float f0 = lds[sp * 65 + npr];
        const float f1 = lds[(sp + 1) * 65 + npr];
        const uint_t packed = (uint_t)f32_to_bf16(f0) | ((uint_t)f32_to_bf16(f1) << 16);
        *(uint_t*)(Xt + ((size_t)b * 256 + nt * 64 + npr) * 2048 + s0 + sp) = packed;
    }
}

// ---------------- stage-1 GEMM + finalize tail ----------------
#define GLOAD_LDS16(gsrc, ldst) \
    __builtin_amdgcn_global_load_lds((const __attribute__((address_space(1))) void*)(gsrc), \
                                     (__attribute__((address_space(3))) void*)(ldst), 16, 0, 0)

__global__ __launch_bounds__(256, 2) void gemm_v(
    const ushort_t* __restrict__ Pb,     // 9*65536 bf16 (e=0..8)
    const ushort_t* __restrict__ Xt,     // [8192][2048] bf16
    ushort_t* __restrict__ vt,           // [8][8192][256] bf16
    const float* __restrict__ ps1, const float* __restrict__ ps2,
    const float* __restrict__ prs, const float* __restrict__ Wenc,
    float* __restrict__ meanv, float* __restrict__ stdv, float* __restrict__ rsA)
{
    __shared__ ushort_t sAa[3][4096];    // A = Xt tile [128 rows x 32k] x3 (24 KB)
    __shared__ ushort_t sBb[3][8192];    // B = power tile [256 rows x 32k] x3 (48 KB)

    const int bid = blockIdx.x;
    const int tid = threadIdx.x;
    if (bid >= 512) {
        const int idx = bid - 512;       // 0..35
        if (idx < 32) {
            const int b = idx;
            float s = 0.f, q = 0.f;
#pragma unroll
            for (int st = 0; st < 32; ++st) {
                s += ps1[(size_t)st * 8192 + b * 256 + tid];
                q += ps2[(size_t)st * 8192 + b * 256 + tid];
            }
            const float mean = s * (1.0f / 2048.0f);
            float var = q * (1.0f / 2048.0f) - mean * mean;
            var = fmaxf(var, 0.0f);
            meanv[b * 256 + tid] = mean;
            stdv [b * 256 + tid] = sqrtf(var + 1e-5f);
        } else {
            const int l = idx - 32;
            float u = 0.f;
#pragma unroll
            for (int k = 0; k < 8; ++k) u += Wenc[l * 8 + k] * prs[(8 - k) * 256 + tid];
            float* uf = (float*)&sAa[0][0];
            uf[tid] = u;
            __syncthreads();
            const uint2* rp = (const uint2*)(Pb + (size_t)l * 65536 + tid * 256);
            float s = 0.f;
#pragma unroll
            for (int i = 0; i < 64; ++i) {
                const uint2 v = rp[i];
                s += bf16_to_f32((ushort_t)(v.x & 0xffff)) * uf[i * 4 + 0]
                   + bf16_to_f32((ushort_t)(v.x >> 16))    * uf[i * 4 + 1]
                   + bf16_to_f32((ushort_t)(v.y & 0xffff)) * uf[i * 4 + 2]
                   + bf16_to_f32((ushort_t)(v.y >> 16))    * uf[i * 4 + 3];
            }
            rsA[l * 256 + tid] = s;
        }
        return;
    }

    // grid 512 = 8 xcd x 8 colT-group x 8 k
    const int xcd  = bid & 7;
    const int g    = bid >> 3;
    const int colT = xcd + ((g & 7) << 3);   // 0..63 (128 Xt rows each)
    const int k    = g >> 3;                 // 0..7
    const int e    = 8 - k;

    const int lane = tid & 63;
    const int w    = tid >> 6;               // 0..3
    const int wm   = w >> 1, wn = w & 1;
    const int li   = lane & 31, lg = lane >> 5;
    const int lq3  = (li >> 1) & 3;
    const int lrow = 2 * (lane >> 3) + ((lane >> 2) & 1);
    const int kc   = (lane & 3) ^ ((lane >> 3) & 3);

    const ushort_t* xtb = Xt + (size_t)(colT * 128) * 2048 + k * 256;
    const ushort_t* pbb = Pb + (size_t)e * 65536;

#define VSTAGE(bf_, kt_) do { \
    const int p0_ = (kt_) * 32 + kc * 8; \
    GLOAD_LDS16(xtb + (size_t)(w * 32 + 0  + lrow) * 2048 + p0_, &sAa[bf_][(w * 32 + 0)  * 32]); \
    GLOAD_LDS16(xtb + (size_t)(w * 32 + 16 + lrow) * 2048 + p0_, &sAa[bf_][(w * 32 + 16) * 32]); \
    GLOAD_LDS16(pbb + (w * 64 + 0  + lrow) * 256 + p0_, &sBb[bf_][(w * 64 + 0)  * 32]); \
    GLOAD_LDS16(pbb + (w * 64 + 16 + lrow) * 256 + p0_, &sBb[bf_][(w * 64 + 16) * 32]); \
    GLOAD_LDS16(pbb + (w * 64 + 32 + lrow) * 256 + p0_, &sBb[bf_][(w * 64 + 32) * 32]); \
    GLOAD_LDS16(pbb + (w * 64 + 48 + lrow) * 256 + p0_, &sBb[bf_][(w * 64 + 48) * 32]); \
} while (0)

    f32x16 acc[2][4];
#pragma unroll
    for (int mm = 0; mm < 2; ++mm)
#pragma unroll
        for (int nn = 0; nn < 4; ++nn)
#pragma unroll
            for (int rr = 0; rr < 16; ++rr) acc[mm][nn][rr] = 0.0f;

    VSTAGE(0, 0);
    VSTAGE(1, 1);

#define VKT(kt_) do { \
    if ((kt_) < 7) { asm volatile("s_waitcnt vmcnt(6)" ::: "memory"); } \
    else           { asm volatile("s_waitcnt vmcnt(0)" ::: "memory"); } \
    __builtin_amdgcn_s_barrier(); \
    asm volatile("" ::: "memory"); \
    const ushort_t* pa_ = &sAa[(kt_) % 3][0]; \
    const ushort_t* px_ = &sBb[(kt_) % 3][0]; \
    bf16x8 af[2][2], xf[2][4]; \
    _Pragma("unroll") \
    for (int ks = 0; ks < 2; ++ks) { \
        const int sl = ((ks << 1) + lg) ^ lq3; \
        const int ro = (li >> 1) * 64 + (li & 1) * 32 + sl * 8; \
        af[ks][0] = *(const bf16x8*)(pa_ + wm * 2048 + ro); \
        af[ks][1] = *(const bf16x8*)(pa_ + wm * 2048 + 1024 + ro); \
        xf[ks][0] = *(const bf16x8*)(px_ + wn * 4096 + ro); \
        xf[ks][1] = *(const bf16x8*)(px_ + wn * 4096 + 1024 + ro); \
        xf[ks][2] = *(const bf16x8*)(px_ + wn * 4096 + 2048 + ro); \
        xf[ks][3] = *(const bf16x8*)(px_ + wn * 4096 + 3072 + ro); \
    } \
    if ((kt_) < 6) { VSTAGE(((kt_) + 2) % 3, (kt_) + 2); } \
    __builtin_amdgcn_s_setprio(1); \
    _Pragma("unroll") \
    for (int ks = 0; ks < 2; ++ks) \
        _Pragma("unroll") \
        for (int mm = 0; mm < 2; ++mm) \
            _Pragma("unroll") \
            for (int nn = 0; nn < 4; ++nn) \
                acc[mm][nn] = __builtin_amdgcn_mfma_f32_32x32x16_bf16(af[ks][mm], xf[ks][nn], acc[mm][nn], 0, 0, 0); \
    __builtin_amdgcn_s_setprio(0); \
    asm volatile("" ::: "memory"); \
} while (0)

    VKT(0); VKT(1); VKT(2); VKT(3); VKT(4); VKT(5); VKT(6); VKT(7);
#undef VKT
#undef VSTAGE

    ushort_t* vb = vt + (size_t)k * 2097152;
#pragma unroll
    for (int mm = 0; mm < 2; ++mm)
#pragma unroll
        for (int nn = 0; nn < 4; ++nn) {
            const int q = wn * 128 + nn * 32 + li;
#pragma unroll
            for (int rr = 0; rr < 16; ++rr) {
                const int c = colT * 128 + wm * 64 + mm * 32 + ((rr & 3) + 8 * (rr >> 2) + 4 * lg);
                vb[(size_t)c * 256 + q] = f32_to_bf16(acc[mm][nn][rr]);
            }
        }
}

// ---------------- stage-2 GEMM with fused in-LDS combine ----------------
// out rows l*256+q' = Pb[l] @ c_l, c_l built per K-step from vt (reg loads ->
// weighted sum -> ds_write macro-row tile). Grid 256 = 128 colH(64 cols) x 2 qc.
// 8 waves (4 l x 2 qh), wave tile 64 q' x 64 cols, acc[2][2].
__global__ __launch_bounds__(512, 2) void gemm2c(
    const ushort_t* __restrict__ Pb, const ushort_t* __restrict__ vt,
    const float* __restrict__ Wenc,
    const float* __restrict__ meanv, const float* __restrict__ stdv,
    const float* __restrict__ rsA, const float* __restrict__ benc,
    float* __restrict__ out)
{
    __shared__ ushort_t sAa[3][16384];   // 3 x [4l][128 q' x 32q] macro = 96 KB
    __shared__ ushort_t sCc[2][8192];    // 2 x [4l][64 col x 32q] macro = 32 KB

    const int bid  = blockIdx.x;         // 0..255
    const int xcd  = bid & 7;
    const int g    = bid >> 3;           // 0..31
    const int colH = xcd + ((g & 15) << 3);  // 0..127 (64 cols each)
    const int qc   = g >> 4;             // 0..1 (q' chunk of 128)

    const int tid  = threadIdx.x;
    const int lane = tid & 63;
    const int w    = tid >> 6;           // 0..7
    const int l    = w & 3;
    const int qh   = w >> 2;             // 0..1
    const int li   = lane & 31, lg = lane >> 5;
    const int lq3  = (li >> 1) & 3;
    const int lrow = 2 * (lane >> 3) + ((lane >> 2) & 1);
    const int kc   = (lane & 3) ^ ((lane >> 3) & 3);

    // combine-thread decode
    const int ccol = tid & 63;
    const int qoct = (tid >> 6) & 3;
    const int rep  = tid >> 8;           // 0..1 -> handles l's {0,1} / {2,3}

    const ushort_t* ab = Pb + (size_t)l * 65536 + (size_t)(qc * 128) * 256;
    const ushort_t* vb = vt + (size_t)(colH * 64 + ccol) * 256;

    float weR[2][8];
#pragma unroll
    for (int j = 0; j < 2; ++j)
#pragma unroll
        for (int k = 0; k < 8; ++k) weR[j][k] = Wenc[(rep * 2 + j) * 8 + k];
    asm volatile("s_waitcnt vmcnt(0)" ::: "memory");

#define AST(bf_, kt_) do { \
    const int p0_ = (kt_) * 32 + kc * 8; \
    _Pragma("unroll") \
    for (int i_ = 0; i_ < 4; ++i_) \
        GLOAD_LDS16(ab + (size_t)(qh * 64 + i_ * 16 + lrow) * 256 + p0_, \
                    &sAa[bf_][l * 4096 + qh * 2048 + i_ * 512]); \
} while (0)

#define VLOAD(dst_, kt_) do { \
    _Pragma("unroll") \
    for (int k_ = 0; k_ < 8; ++k_) \
        dst_[k_] = *(const bf16x8*)(vb + (size_t)k_ * 2097152 + (kt_) * 32 + qoct * 8); \
} while (0)

#define COMB(src_, cb_) do { \
    _Pragma("unroll") \
    for (int j_ = 0; j_ < 2; ++j_) { \
        float s_[8] = {0,0,0,0,0,0,0,0}; \
        _Pragma("unroll") \
        for (int k_ = 0; k_ < 8; ++k_) { \
            const float w_ = weR[j_][k_]; \
            _Pragma("unroll") \
            for (int q_ = 0; q_ < 8; ++q_) \
                s_[q_] += w_ * bf16_to_f32((ushort_t)src_[k_][q_]); \
        } \
        uint4 o_; \
        o_.x = (uint_t)f32_to_bf16(s_[0]) | ((uint_t)f32_to_bf16(s_[1]) << 16); \
        o_.y = (uint_t)f32_to_bf16(s_[2]) | ((uint_t)f32_to_bf16(s_[3]) << 16); \
        o_.z = (uint_t)f32_to_bf16(s_[4]) | ((uint_t)f32_to_bf16(s_[5]) << 16); \
        o_.w = (uint_t)f32_to_bf16(s_[6]) | ((uint_t)f32_to_bf16(s_[7]) << 16); \
        const int le_ = (rep * 2 + j_) * 2048 + (ccol >> 1) * 64 + (ccol & 1) * 32 \
                      + ((qoct ^ ((ccol >> 1) & 3)) * 8); \
        *(uint4*)(&sCc[cb_][le_]) = o_; \
    } \
} while (0)

    f32x16 acc[2][2];
#pragma unroll
    for (int mm = 0; mm < 2; ++mm)
#pragma unroll
        for (int nn = 0; nn < 2; ++nn)
#pragma unroll
            for (int rr = 0; rr < 16; ++rr) acc[mm][nn][rr] = 0.0f;

    bf16x8 vvA[8], vvB[8];
    AST(0, 0);                 // +4 vm per wave
    VLOAD(vvA, 0);             // +8 vm

#define G2KT(kt_, cur_, nxt_) do { \
    if ((kt_) < 7) { \
        AST(((kt_) + 1) % 3, (kt_) + 1); \
        VLOAD(nxt_, (kt_) + 1); \
        asm volatile("s_waitcnt vmcnt(12)" ::: "memory"); \
    } else { \
        asm volatile("s_waitcnt vmcnt(0)" ::: "memory"); \
    } \
    COMB(cur_, (kt_) & 1); \
    asm volatile("s_waitcnt lgkmcnt(0)" ::: "memory"); \
    __builtin_amdgcn_s_barrier(); \
    asm volatile("" ::: "memory"); \
    const ushort_t* pa_ = &sAa[(kt_) % 3][l * 4096 + qh * 2048]; \
    const ushort_t* px_ = &sCc[(kt_) & 1][l * 2048]; \
    __builtin_amdgcn_s_setprio(1); \
    _Pragma("unroll") \
    for (int ks_ = 0; ks_ < 2; ++ks_) { \
        const int sl_ = (ks_ * 2 + lg) ^ lq3; \
        const int ro_ = (li >> 1) * 64 + (li & 1) * 32 + sl_ * 8; \
        const bf16x8 a0_ = *(const bf16x8*)(pa_ + ro_); \
        const bf16x8 a1_ = *(const bf16x8*)(pa_ + 1024 + ro_); \
        const bf16x8 x0_ = *(const bf16x8*)(px_ + ro_); \
        const bf16x8 x1_ = *(const bf16x8*)(px_ + 1024 + ro_); \
        acc[0][0] = __builtin_amdgcn_mfma_f32_32x32x16_bf16(a0_, x0_, acc[0][0], 0, 0, 0); \
        acc[0][1] = __builtin_amdgcn_mfma_f32_32x32x16_bf16(a0_, x1_, acc[0][1], 0, 0, 0); \
        acc[1][0] = __builtin_amdgcn_mfma_f32_32x32x16_bf16(a1_, x0_, acc[1][0], 0, 0, 0); \
        acc[1][1] = __builtin_amdgcn_mfma_f32_32x32x16_bf16(a1_, x1_, acc[1][1], 0, 0, 0); \
    } \
    __builtin_amdgcn_s_setprio(0); \
    asm volatile("" ::: "memory"); \
} while (0)

    G2KT(0, vvA, vvB); G2KT(1, vvB, vvA); G2KT(2, vvA, vvB); G2KT(3, vvB, vvA);
    G2KT(4, vvA, vvB); G2KT(5, vvB, vvA); G2KT(6, vvA, vvB); G2KT(7, vvB, vvA);
#undef G2KT
#undef COMB
#undef VLOAD
#undef AST

    // epilogue: out = acc + mean*(1-rsA) + benc[l]*std
    const float be = benc[l];
    float mn[2], sd[2];
#pragma unroll
    for (int nn = 0; nn < 2; ++nn) {
        const int col = colH * 64 + nn * 32 + li;
        mn[nn] = meanv[col];
        sd[nn] = stdv [col];
    }
#pragma unroll
    for (int mm = 0; mm < 2; ++mm)
#pragma unroll
        for (int nn = 0; nn < 2; ++nn) {
            const int col = colH * 64 + nn * 32 + li;
            const int bq = col >> 8, nq = col & 255;
            const float ben = be * sd[nn];
#pragma unroll
            for (int rr = 0; rr < 16; ++rr) {
                const int trow = l * 256 + qc * 128 + qh * 64 + mm * 32
                               + ((rr & 3) + 8 * (rr >> 2) + 4 * lg);
                out[((size_t)bq * 1024 + trow) * 256 + nq] =
                    acc[mm][nn][rr] + mn[nn] * (1.0f - rsA[trow]) + ben;
            }
        }
}

// ---------------- launch ----------------
extern "C" void kernel_launch(void* const* d_in, const int* in_sizes, int n_in,
                              void* d_out, int out_size, void* d_ws, size_t ws_size,
                              hipStream_t stream) {
    (void)in_sizes; (void)n_in; (void)out_size; (void)ws_size;
    const float* x_enc  = (const float*)d_in[0];
    const float* W_base = (const float*)d_in[4];
    const float* W_enc  = (const float*)d_in[5];
    const float* b_enc  = (const float*)d_in[6];
    float* out = (float*)d_out;

    char* ws = (char*)d_ws;
    float*    wsP    = (float*)(ws);                  // 3*65536 f32 (W2,W3,W4)
    ushort_t* wsPb   = (ushort_t*)(ws + 0x200000);    // 9*65536 bf16 (I..W^8)
    float*    wsPrs  = (float*)(ws + 0x340000);       // 9*256 f32
    float*    wsS1   = (float*)(ws + 0x350000);       // 32*8192 f32 (1 MB)
    float*    wsS2   = (float*)(ws + 0x450000);       // 1 MB
    float*    wsMean = (float*)(ws + 0x550000);       // 8192 f32
    float*    wsStd  = (float*)(ws + 0x560000);
    float*    wsRsA  = (float*)(ws + 0x570000);       // 1024 f32
    ushort_t* wsXt   = (ushort_t*)(ws + 0x600000);    // [8192][2048] bf16 (32 MB)
    ushort_t* wsVt   = (ushort_t*)(ws + 0x2600000);   // [8][8192][256] bf16 (32 MB)

    // L1: W2 (f32 slot0 + Pb[2]) | copy W -> Pb[1] | identity -> Pb[0]
    { PowOps o{{-1, -3, -2, 0}, {-1, 0, 0, 0}, {0, -1, -1, 0}, {2, 1, 0, 0}};
      powmulc<<<dim3(3, 64), 256, 0, stream>>>(W_base, wsP, wsPb, wsPrs, o); }
    // L2: W3 = W2*W (slot1, Pb[3]) | W4 = W2*W2 (slot2, Pb[4])
    { PowOps o{{0, 0, 0, 0}, {-1, 0, 0, 0}, {1, 2, 0, 0}, {3, 4, 0, 0}};
      powmulc<<<dim3(2, 64), 256, 0, stream>>>(W_base, wsP, wsPb, wsPrs, o); }
    // L3: W5..W8 = W4*{W,W2,W3,W4} (bf16 only -> Pb[5..8])
    { PowOps o{{2, 2, 2, 2}, {-1, 0, 1, 2}, {-1, -1, -1, -1}, {5, 6, 7, 8}};
      powmulc<<<dim3(4, 64), 256, 0, stream>>>(W_base, wsP, wsPb, wsPrs, o); }

    prep<<<4096, 256, 0, stream>>>(x_enc, wsXt, wsS1, wsS2);

    gemm_v<<<548, 256, 0, stream>>>(wsPb, wsXt, wsVt, wsS1, wsS2, wsPrs, W_enc,
                                    wsMean, wsStd, wsRsA);

    gemm2c<<<256, 512, 0, stream>>>(wsPb, wsVt, W_enc, wsMean, wsStd, wsRsA,
                                    b_enc, out);
}

// Round 15
// 104.021 us; speedup vs baseline: 1.1734x; 1.1734x over previous
//
#include <hip/hip_runtime.h>
#include <cstdint>
#include <cstddef>

// B=32, S=2048, P=256, N=256, K=8, L=4, M_out=1024
// Factorized: v_k = bf16(W^{8-k}) @ X   (stage 1, reads transposed Xt)
//             c_l = sum_k W_enc[l,k] v_k (streaming combine + finalize)
//             dec[l] = bf16(W^l) @ c_l   (stage 2; W^0 = I exact)
// out = dec + mean*(1-rowsumA) + b_enc*std  (affine fold; rowsums of ROUNDED maps)
// R15 = R13 (proven 99.6us) + the 3-launch power chain fused INTO prep's launch:
// each W^e computed independently per block by row-chained products (e-1 steps,
// 4 rows/block through LDS ping-pong; W L2-hot). Power blocks grid-front so they
// hide under prep's HBM-bound 16us. gemm_v/combine/gemm2 r13-verbatim.

typedef unsigned short ushort_t;
typedef unsigned int uint_t;
typedef __attribute__((ext_vector_type(8))) short bf16x8;
typedef __attribute__((ext_vector_type(16))) float f32x16;

__device__ __forceinline__ ushort_t f32_to_bf16(float f) {
    uint_t u = __float_as_uint(f);
    u += 0x7FFFu + ((u >> 16) & 1u);   // RNE
    return (ushort_t)(u >> 16);
}
__device__ __forceinline__ float bf16_to_f32(ushort_t h) {
    return __uint_as_float((uint_t)h << 16);
}

// ---------------- union kernel: W-powers (bids 0..575) | transpose+stats (576..4671) ----------------
// Powers: block = (e = bid/64, r0 = (bid%64)*4). row_r(W^e) via e-1 sequential
// row-block x W products. Outputs Pb[e] bf16 + prs[e] rowsums (of ROUNDED rows).
__global__ void prep_pow(const float* __restrict__ x, ushort_t* __restrict__ Xt,
                         float* __restrict__ ps1, float* __restrict__ ps2,
                         const float* __restrict__ Wb,
                         ushort_t* __restrict__ Pb, float* __restrict__ prs) {
    __shared__ float shmem[64 * 65 + 2048];    // prep: lds|red1|red2; powers: R|red
    const int bid = blockIdx.x;
    const int tid = threadIdx.x;

    if (bid < 576) {
        const int e  = bid >> 6;               // 0..8
        const int r0 = (bid & 63) * 4;
        float a[4];
        if (e == 0) {
#pragma unroll
            for (int i = 0; i < 4; ++i) a[i] = (r0 + i == tid) ? 1.0f : 0.0f;
        } else {
#pragma unroll
            for (int i = 0; i < 4; ++i) a[i] = Wb[(size_t)(r0 + i) * 256 + tid];
            if (e >= 2) {
                float* R = shmem;              // [4][256]
                for (int step = 0; step < e - 1; ++step) {
                    __syncthreads();
#pragma unroll
                    for (int i = 0; i < 4; ++i) R[i * 256 + tid] = a[i];
                    __syncthreads();
                    float n0 = 0.f, n1 = 0.f, n2 = 0.f, n3 = 0.f;
                    for (int p = 0; p < 256; p += 8) {
                        float bv[8];
#pragma unroll
                        for (int u = 0; u < 8; ++u) bv[u] = Wb[(size_t)(p + u) * 256 + tid];
#pragma unroll
                        for (int u = 0; u < 8; ++u) {
                            n0 += R[0 * 256 + p + u] * bv[u];
                            n1 += R[1 * 256 + p + u] * bv[u];
                            n2 += R[2 * 256 + p + u] * bv[u];
                            n3 += R[3 * 256 + p + u] * bv[u];
                        }
                    }
                    a[0] = n0; a[1] = n1; a[2] = n2; a[3] = n3;
                }
            }
        }
        // convert + store + rowsums of ROUNDED rows
        const int lane = tid & 63, wv = tid >> 6;
        float rs[4];
#pragma unroll
        for (int i = 0; i < 4; ++i) {
            const ushort_t h = f32_to_bf16(a[i]);
            Pb[(size_t)e * 65536 + (size_t)(r0 + i) * 256 + tid] = h;
            float v = bf16_to_f32(h);
            v += __shfl_xor(v, 1);  v += __shfl_xor(v, 2);  v += __shfl_xor(v, 4);
            v += __shfl_xor(v, 8);  v += __shfl_xor(v, 16); v += __shfl_xor(v, 32);
            rs[i] = v;
        }
        __syncthreads();
        float* red = shmem;                    // [4][4]
        if (lane == 0) {
#pragma unroll
            for (int i = 0; i < 4; ++i) red[i * 4 + wv] = rs[i];
        }
        __syncthreads();
        if (tid < 4) prs[e * 256 + r0 + tid] = red[tid * 4 + 0] + red[tid * 4 + 1]
                                             + red[tid * 4 + 2] + red[tid * 4 + 3];
        return;
    }

    // ---------------- prep: transpose RAW x + bf16 convert + stats partials ----------------
    const int pb = bid - 576;
    const int st = pb & 31;
    const int nt = (pb >> 5) & 3;
    const int b  = pb >> 7;
    float* lds  = shmem;                       // [64*65]
    float* red1 = shmem + 64 * 65;             // [16*64]... packed into +2048 tail? no:
    // NOTE: red1/red2 need 2048 floats; lds needs 4160. Total 6208 <= 64*65+2048.
    float* red2 = red1 + 1024;
    const int c = tid & 15, r = tid >> 4;
    const int s0 = st * 64;
    float s1[4] = {0,0,0,0}, s2[4] = {0,0,0,0};
#pragma unroll
    for (int it = 0; it < 4; ++it) {
        const int ii = r + it * 16;
        const float4 v = *(const float4*)(x + ((size_t)b * 2048 + s0 + ii) * 256 + nt * 64 + c * 4);
        const float vv[4] = {v.x, v.y, v.z, v.w};
#pragma unroll
        for (int jj = 0; jj < 4; ++jj) {
            lds[ii * 65 + c * 4 + jj] = vv[jj];
            s1[jj] += vv[jj]; s2[jj] += vv[jj] * vv[jj];
        }
    }
    // cross-thread reduce via wave shuffles to avoid colliding with lds[]:
    // thread (r,c) holds partials for n-cols c*4..c*4+3 over its 4 s-rows.
    // Reduce over r (16 values) -> lanes with same c. r = tid>>4: lanes r*16..
    // Simpler: keep r13's LDS-based reduce but in the tail region red1/red2.
#pragma unroll
    for (int jj = 0; jj < 4; ++jj) { red1[r * 64 + c * 4 + jj] = s1[jj]; red2[r * 64 + c * 4 + jj] = s2[jj]; }
    __syncthreads();
    if (tid < 64) {
        float a = 0.f, q = 0.f;
#pragma unroll
        for (int rr = 0; rr < 16; ++rr) { a += red1[rr * 64 + tid]; q += red2[rr * 64 + tid]; }
        const size_t o = (size_t)st * 8192 + b * 256 + nt * 64 + tid;
        ps1[o] = a; ps2[o] = q;
    }
#pragma unroll
    for (int step = 0; step < 8; ++step) {
        const int npr = step * 8 + (tid >> 5);
        const int sp  = (tid & 31) * 2;
        const float f0 = lds[sp * 65 + npr];
        const float f1 = lds[(sp + 1) * 65 + npr];
        const uint_t packed = (uint_t)f32_to_bf16(f0) | ((uint_t)f32_to_bf16(f1) << 16);
        *(uint_t*)(Xt + ((size_t)b * 256 + nt * 64 + npr) * 2048 + s0 + sp) = packed;
    }
}

// ---------------- stage-1 GEMM: vt[k][col][q] = (Xt_colslice @ Pb[8-k]^T) ----------------
#define GLOAD_LDS16(gsrc, ldst) \
    __builtin_amdgcn_global_load_lds((const __attribute__((address_space(1))) void*)(gsrc), \
                                     (__attribute__((address_space(3))) void*)(ldst), 16, 0, 0)

__global__ __launch_bounds__(256, 2) void gemm_v(
    const ushort_t* __restrict__ Pb,     // 9*65536 bf16 (e=0..8)
    const ushort_t* __restrict__ Xt,     // [8192][2048] bf16
    ushort_t* __restrict__ vt)           // [8][8192][256] bf16
{
    __shared__ ushort_t sAa[3][4096];    // A = Xt tile [128 rows x 32k] x3 (24 KB)
    __shared__ ushort_t sBb[3][8192];    // B = power tile [256 rows x 32k] x3 (48 KB)

    const int bid = blockIdx.x;
    const int tid = threadIdx.x;

    // grid 512 = 8 xcd x 8 colT-group x 8 k
    const int xcd  = bid & 7;
    const int g    = bid >> 3;
    const int colT = xcd + ((g & 7) << 3);   // 0..63 (128 Xt rows each)
    const int k    = g >> 3;                 // 0..7
    const int e    = 8 - k;

    const int lane = tid & 63;
    const int w    = tid >> 6;               // 0..3
    const int wm   = w >> 1, wn = w & 1;
    const int li   = lane & 31, lg = lane >> 5;
    const int lq3  = (li >> 1) & 3;
    const int lrow = 2 * (lane >> 3) + ((lane >> 2) & 1);
    const int kc   = (lane & 3) ^ ((lane >> 3) & 3);

    const ushort_t* xtb = Xt + (size_t)(colT * 128) * 2048 + k * 256;  // + row*2048 + p
    const ushort_t* pbb = Pb + (size_t)e * 65536;                      // + q*256 + p

#define VSTAGE(bf_, kt_) do { \
    const int p0_ = (kt_) * 32 + kc * 8; \
    GLOAD_LDS16(xtb + (size_t)(w * 32 + 0  + lrow) * 2048 + p0_, &sAa[bf_][(w * 32 + 0)  * 32]); \
    GLOAD_LDS16(xtb + (size_t)(w * 32 + 16 + lrow) * 2048 + p0_, &sAa[bf_][(w * 32 + 16) * 32]); \
    GLOAD_LDS16(pbb + (w * 64 + 0  + lrow) * 256 + p0_, &sBb[bf_][(w * 64 + 0)  * 32]); \
    GLOAD_LDS16(pbb + (w * 64 + 16 + lrow) * 256 + p0_, &sBb[bf_][(w * 64 + 16) * 32]); \
    GLOAD_LDS16(pbb + (w * 64 + 32 + lrow) * 256 + p0_, &sBb[bf_][(w * 64 + 32) * 32]); \
    GLOAD_LDS16(pbb + (w * 64 + 48 + lrow) * 256 + p0_, &sBb[bf_][(w * 64 + 48) * 32]); \
} while (0)

    f32x16 acc[2][4];
#pragma unroll
    for (int mm = 0; mm < 2; ++mm)
#pragma unroll
        for (int nn = 0; nn < 4; ++nn)
#pragma unroll
            for (int rr = 0; rr < 16; ++rr) acc[mm][nn][rr] = 0.0f;

    VSTAGE(0, 0);
    VSTAGE(1, 1);

#define VKT(kt_) do { \
    if ((kt_) < 7) { asm volatile("s_waitcnt vmcnt(6)" ::: "memory"); } \
    else           { asm volatile("s_waitcnt vmcnt(0)" ::: "memory"); } \
    __builtin_amdgcn_s_barrier(); \
    asm volatile("" ::: "memory"); \
    const ushort_t* pa_ = &sAa[(kt_) % 3][0]; \
    const ushort_t* px_ = &sBb[(kt_) % 3][0]; \
    bf16x8 af[2][2], xf[2][4]; \
    _Pragma("unroll") \
    for (int ks = 0; ks < 2; ++ks) { \
        const int sl = ((ks << 1) + lg) ^ lq3; \
        const int ro = (li >> 1) * 64 + (li & 1) * 32 + sl * 8; \
        af[ks][0] = *(const bf16x8*)(pa_ + wm * 2048 + ro); \
        af[ks][1] = *(const bf16x8*)(pa_ + wm * 2048 + 1024 + ro); \
        xf[ks][0] = *(const bf16x8*)(px_ + wn * 4096 + ro); \
        xf[ks][1] = *(const bf16x8*)(px_ + wn * 4096 + 1024 + ro); \
        xf[ks][2] = *(const bf16x8*)(px_ + wn * 4096 + 2048 + ro); \
        xf[ks][3] = *(const bf16x8*)(px_ + wn * 4096 + 3072 + ro); \
    } \
    if ((kt_) < 6) { VSTAGE(((kt_) + 2) % 3, (kt_) + 2); } \
    __builtin_amdgcn_s_setprio(1); \
    _Pragma("unroll") \
    for (int ks = 0; ks < 2; ++ks) \
        _Pragma("unroll") \
        for (int mm = 0; mm < 2; ++mm) \
            _Pragma("unroll") \
            for (int nn = 0; nn < 4; ++nn) \
                acc[mm][nn] = __builtin_amdgcn_mfma_f32_32x32x16_bf16(af[ks][mm], xf[ks][nn], acc[mm][nn], 0, 0, 0); \
    __builtin_amdgcn_s_setprio(0); \
    asm volatile("" ::: "memory"); \
} while (0)

    VKT(0); VKT(1); VKT(2); VKT(3); VKT(4); VKT(5); VKT(6); VKT(7);
#undef VKT
#undef VSTAGE

    // epilogue: vt[k][col][q] bf16 (lane li = q -> contiguous 64B stores)
    ushort_t* vb = vt + (size_t)k * 2097152;
#pragma unroll
    for (int mm = 0; mm < 2; ++mm)
#pragma unroll
        for (int nn = 0; nn < 4; ++nn) {
            const int q = wn * 128 + nn * 32 + li;
#pragma unroll
            for (int rr = 0; rr < 16; ++rr) {
                const int c = colT * 128 + wm * 64 + mm * 32 + ((rr & 3) + 8 * (rr >> 2) + 4 * lg);
                vb[(size_t)c * 256 + q] = f32_to_bf16(acc[mm][nn][rr]);
            }
        }
}

// ---------------- combine: c_l = sum_k we*v_k | finalize mean/std | rsA ----------------
__global__ void combine(const ushort_t* __restrict__ vt, const float* __restrict__ Wenc,
                        ushort_t* __restrict__ c,
                        const float* __restrict__ ps1, const float* __restrict__ ps2,
                        const float* __restrict__ prs, const ushort_t* __restrict__ Pb,
                        float* __restrict__ meanv, float* __restrict__ stdv,
                        float* __restrict__ rsA) {
    __shared__ float uf[256];
    const int bid = blockIdx.x;
    const int t   = threadIdx.x;
    if (bid < 1024) {
        const int col = bid * 8 + (t >> 5);
        const size_t off = (size_t)col * 256 + (t & 31) * 8;
        float a0[8] = {0,0,0,0,0,0,0,0}, a1[8] = {0,0,0,0,0,0,0,0};
        float a2[8] = {0,0,0,0,0,0,0,0}, a3[8] = {0,0,0,0,0,0,0,0};
#pragma unroll
        for (int k = 0; k < 8; ++k) {
            const bf16x8 v = *(const bf16x8*)(vt + (size_t)k * 2097152 + off);
            const float w0 = Wenc[0 * 8 + k], w1 = Wenc[1 * 8 + k];
            const float w2 = Wenc[2 * 8 + k], w3 = Wenc[3 * 8 + k];
#pragma unroll
            for (int j = 0; j < 8; ++j) {
                const float f = bf16_to_f32((ushort_t)v[j]);
                a0[j] += w0 * f; a1[j] += w1 * f; a2[j] += w2 * f; a3[j] += w3 * f;
            }
        }
        bf16x8 o0, o1, o2, o3;
#pragma unroll
        for (int j = 0; j < 8; ++j) {
            o0[j] = (short)f32_to_bf16(a0[j]); o1[j] = (short)f32_to_bf16(a1[j]);
            o2[j] = (short)f32_to_bf16(a2[j]); o3[j] = (short)f32_to_bf16(a3[j]);
        }
        *(bf16x8*)(c + 0 * 2097152 + off) = o0;
        *(bf16x8*)(c + 1 * 2097152 + off) = o1;
        *(bf16x8*)(c + 2 * 2097152 + off) = o2;
        *(bf16x8*)(c + 3 * 2097152 + off) = o3;
    } else if (bid < 1056) {
        const int b = bid - 1024;            // 0..31
        float s = 0.f, q = 0.f;
#pragma unroll
        for (int st = 0; st < 32; ++st) {
            s += ps1[(size_t)st * 8192 + b * 256 + t];
            q += ps2[(size_t)st * 8192 + b * 256 + t];
        }
        const float mean = s * (1.0f / 2048.0f);
        float var = q * (1.0f / 2048.0f) - mean * mean;
        var = fmaxf(var, 0.0f);
        meanv[b * 256 + t] = mean;
        stdv [b * 256 + t] = sqrtf(var + 1e-5f);
    } else {
        const int l = bid - 1056;            // 0..3
        float u = 0.f;
#pragma unroll
        for (int k = 0; k < 8; ++k) u += Wenc[l * 8 + k] * prs[(8 - k) * 256 + t];
        uf[t] = u;
        __syncthreads();
        const uint2* rp = (const uint2*)(Pb + (size_t)l * 65536 + t * 256);
        float s = 0.f;
#pragma unroll
        for (int i = 0; i < 64; ++i) {
            const uint2 v = rp[i];
            s += bf16_to_f32((ushort_t)(v.x & 0xffff)) * uf[i * 4 + 0]
               + bf16_to_f32((ushort_t)(v.x >> 16))    * uf[i * 4 + 1]
               + bf16_to_f32((ushort_t)(v.y & 0xffff)) * uf[i * 4 + 2]
               + bf16_to_f32((ushort_t)(v.y >> 16))    * uf[i * 4 + 3];
        }
        rsA[l * 256 + t] = s;
    }
}

// ---------------- stage-2 GEMM: out rows l*256+q' = Pb[l] @ c_l, affine epilogue ----------------
__global__ __launch_bounds__(256, 2) void gemm2(
    const ushort_t* __restrict__ Pb, const ushort_t* __restrict__ c,
    const float* __restrict__ meanv, const float* __restrict__ stdv,
    const float* __restrict__ rsA, const float* __restrict__ benc,
    float* __restrict__ out)
{
    __shared__ ushort_t sAa[3][4096];
    __shared__ ushort_t sBb[3][4096];

    const int bid  = blockIdx.x;             // 0..511
    const int xcd  = bid & 7;
    const int g    = bid >> 3;
    const int colT = xcd + ((g & 7) << 3);   // 0..63
    const int rest = g >> 3;                 // 0..7
    const int l    = rest >> 1;
    const int qpT  = rest & 1;

    const int tid  = threadIdx.x;
    const int lane = tid & 63;
    const int w    = tid >> 6;
    const int wm   = w >> 1, wn = w & 1;
    const int li   = lane & 31, lg = lane >> 5;
    const int lq3  = (li >> 1) & 3;
    const int lrow = 2 * (lane >> 3) + ((lane >> 2) & 1);
    const int kc   = (lane & 3) ^ ((lane >> 3) & 3);

    const ushort_t* ab = Pb + (size_t)l * 65536 + (size_t)(qpT * 128) * 256;
    const ushort_t* cb = c + ((size_t)l * 8192 + colT * 128) * 256;

#define GSTAGE(bf_, kt_) do { \
    const int p0_ = (kt_) * 32 + kc * 8; \
    GLOAD_LDS16(ab + (w * 32 + 0  + lrow) * 256 + p0_, &sAa[bf_][(w * 32 + 0)  * 32]); \
    GLOAD_LDS16(ab + (w * 32 + 16 + lrow) * 256 + p0_, &sAa[bf_][(w * 32 + 16) * 32]); \
    GLOAD_LDS16(cb + (w * 32 + 0  + lrow) * 256 + p0_, &sBb[bf_][(w * 32 + 0)  * 32]); \
    GLOAD_LDS16(cb + (w * 32 + 16 + lrow) * 256 + p0_, &sBb[bf_][(w * 32 + 16) * 32]); \
} while (0)

    f32x16 acc[2][2];
#pragma unroll
    for (int mm = 0; mm < 2; ++mm)
#pragma unroll
        for (int nn = 0; nn < 2; ++nn)
#pragma unroll
            for (int rr = 0; rr < 16; ++rr) acc[mm][nn][rr] = 0.0f;

    GSTAGE(0, 0);
    GSTAGE(1, 1);

#define GKT(kt_) do { \
    if ((kt_) < 7) { asm volatile("s_waitcnt vmcnt(4)" ::: "memory"); } \
    else           { asm volatile("s_waitcnt vmcnt(0)" ::: "memory"); } \
    __builtin_amdgcn_s_barrier(); \
    asm volatile("" ::: "memory"); \
    const ushort_t* pa_ = &sAa[(kt_) % 3][0]; \
    const ushort_t* px_ = &sBb[(kt_) % 3][0]; \
    bf16x8 af[2][2], xf[2][2]; \
    _Pragma("unroll") \
    for (int ks = 0; ks < 2; ++ks) { \
        const int sl = ((ks << 1) + lg) ^ lq3; \
        const int ro = (li >> 1) * 64 + (li & 1) * 32 + sl * 8; \
        af[ks][0] = *(const bf16x8*)(pa_ + wm * 2048 + ro); \
        af[ks][1] = *(const bf16x8*)(pa_ + wm * 2048 + 1024 + ro); \
        xf[ks][0] = *(const bf16x8*)(px_ + wn * 2048 + ro); \
        xf[ks][1] = *(const bf16x8*)(px_ + wn * 2048 + 1024 + ro); \
    } \
    if ((kt_) < 6) { GSTAGE(((kt_) + 2) % 3, (kt_) + 2); } \
    __builtin_amdgcn_s_setprio(1); \
    _Pragma("unroll") \
    for (int ks = 0; ks < 2; ++ks) { \
        acc[0][0] = __builtin_amdgcn_mfma_f32_32x32x16_bf16(af[ks][0], xf[ks][0], acc[0][0], 0, 0, 0); \
        acc[0][1] = __builtin_amdgcn_mfma_f32_32x32x16_bf16(af[ks][0], xf[ks][1], acc[0][1], 0, 0, 0); \
        acc[1][0] = __builtin_amdgcn_mfma_f32_32x32x16_bf16(af[ks][1], xf[ks][0], acc[1][0], 0, 0, 0); \
        acc[1][1] = __builtin_amdgcn_mfma_f32_32x32x16_bf16(af[ks][1], xf[ks][1], acc[1][1], 0, 0, 0); \
    } \
    __builtin_amdgcn_s_setprio(0); \
    asm volatile("" ::: "memory"); \
} while (0)

    GKT(0); GKT(1); GKT(2); GKT(3); GKT(4); GKT(5); GKT(6); GKT(7);
#undef GKT
#undef GSTAGE

    const float be = benc[l];
    float mn[2], sd[2];
#pragma unroll
    for (int nn = 0; nn < 2; ++nn) {
        const int col = colT * 128 + wn * 64 + nn * 32 + li;
        mn[nn] = meanv[col];
        sd[nn] = stdv [col];
    }
#pragma unroll
    for (int mm = 0; mm < 2; ++mm)
#pragma unroll
        for (int nn = 0; nn < 2; ++nn) {
            const int col = colT * 128 + wn * 64 + nn * 32 + li;
            const int bq = col >> 8, nq = col & 255;
            const float ben = be * sd[nn];
#pragma unroll
            for (int rr = 0; rr < 16; ++rr) {
                const int trow = l * 256 + qpT * 128 + wm * 64 + mm * 32
                               + ((rr & 3) + 8 * (rr >> 2) + 4 * lg);
                out[((size_t)bq * 1024 + trow) * 256 + nq] =
                    acc[mm][nn][rr] + mn[nn] * (1.0f - rsA[trow]) + ben;
            }
        }
}

// ---------------- launch ----------------
extern "C" void kernel_launch(void* const* d_in, const int* in_sizes, int n_in,
                              void* d_out, int out_size, void* d_ws, size_t ws_size,
                              hipStream_t stream) {
    (void)in_sizes; (void)n_in; (void)out_size; (void)ws_size;
    const float* x_enc  = (const float*)d_in[0];
    const float* W_base = (const float*)d_in[4];
    const float* W_enc  = (const float*)d_in[5];
    const float* b_enc  = (const float*)d_in[6];
    float* out = (float*)d_out;

    char* ws = (char*)d_ws;
    ushort_t* wsPb   = (ushort_t*)(ws + 0x200000);    // 9*65536 bf16 (I..W^8)
    float*    wsPrs  = (float*)(ws + 0x340000);       // 9*256 f32
    float*    wsS1   = (float*)(ws + 0x350000);       // 32*8192 f32 (1 MB)
    float*    wsS2   = (float*)(ws + 0x450000);       // 1 MB
    float*    wsMean = (float*)(ws + 0x550000);       // 8192 f32
    float*    wsStd  = (float*)(ws + 0x560000);
    float*    wsRsA  = (float*)(ws + 0x570000);       // 1024 f32
    ushort_t* wsXt   = (ushort_t*)(ws + 0x600000);    // [8192][2048] bf16 (32 MB)
    ushort_t* wsC    = (ushort_t*)(ws + 0x600000);    // c aliases Xt (dead after gemm_v)
    ushort_t* wsVt   = (ushort_t*)(ws + 0x2600000);   // [8][8192][256] bf16 (32 MB)

    prep_pow<<<4672, 256, 0, stream>>>(x_enc, wsXt, wsS1, wsS2, W_base, wsPb, wsPrs);

    gemm_v<<<512, 256, 0, stream>>>(wsPb, wsXt, wsVt);

    combine<<<1060, 256, 0, stream>>>(wsVt, W_enc, wsC, wsS1, wsS2, wsPrs, wsPb,
                                      wsMean, wsStd, wsRsA);

    gemm2<<<512, 256, 0, stream>>>(wsPb, wsC, wsMean, wsStd, wsRsA, b_enc, out);
}